// Round 12
// baseline (5267.153 us; speedup 1.0000x reference)
//
#include <hip/hip_runtime.h>

// Soft product quantizer — two-kernel f16-dot2 pipeline (scratch-free).
// z:(8,384,32,32) f32, C:(2048,384) f32. 4096 pairs (n, n+4096) x K=8, d=48, M=2048.
// s = 2<x,c> - |c|^2 (x^2 cancels; |s| small -> no max-subtract).
// K1 (stats): Z = sum e^s, T = sum e^s*s per row -> ws[(k<<13)+n] = (1/Z, ent).
// K2 (out):   recompute s, O = sum e^s*c (v_pk_fma_f16), cross-JSD, store.
// Lanes: pr=lane&7 (pair), cs=lane>>3 (codes m ≡ cs mod 8; per-instr LDS
// addresses spaced 112B -> banks 28*dcs mod 32 all distinct: conflict-free).
// Each lane handles BOTH rows of its pair (one code-read serves p and q).
// RULE-20 DISCIPLINE: no runtime-indexed register arrays, no register arrays
// passed by pointer — all hot-loop array indices are compile-time (macros).

typedef __fp16 f16;
typedef __attribute__((ext_vector_type(2))) __fp16 f16x2;

#define Z_BCH   (384*1024)
#define JSD_IDX 3145728

__device__ __forceinline__ f16x2 u2h(unsigned u) {
    union { unsigned u; f16x2 h; } c; c.u = u; return c.h;
}
__device__ __forceinline__ unsigned h2u(f16x2 h) {
    union { f16x2 h; unsigned u; } c; c.h = h; return c.u;
}
__device__ __forceinline__ float fdot2f(f16x2 a, f16x2 b, float c) {
#if __has_builtin(__builtin_amdgcn_fdot2)
    return __builtin_amdgcn_fdot2(a, b, c, false);
#else
    return fmaf((float)a.y, (float)b.y, fmaf((float)a.x, (float)b.x, c));
#endif
}

// ---- shared structure macros (both kernels declare the same locals) ----
#define PQ_PROLOG                                                             \
    const int tid  = threadIdx.x;                                             \
    const int lane = tid & 63;                                                \
    const int wv   = tid >> 6;                                                \
    const int pr   = lane & 7;                                                \
    const int cs   = lane >> 3;          /* 0..7 */                           \
    const int pg   = blockIdx.x & 127;                                        \
    const int k    = blockIdx.x >> 7;                                         \
    const int pairIdx = pg*32 + wv*8 + pr;                                    \
    const size_t basep = (size_t)(pairIdx >> 10)*Z_BCH + (pairIdx & 1023);    \
    const int nq = pairIdx + 4096;                                            \
    const size_t baseq = (size_t)(nq >> 10)*Z_BCH + (nq & 1023);              \
    f16x2 xp[26], xq[26];                                                     \
    _Pragma("unroll")                                                         \
    for (int j = 0; j < 24; ++j) {                                            \
        xp[j] = __builtin_amdgcn_cvt_pkrtz(                                   \
            2.f*Zin[basep + (size_t)(k*48 + 2*j)*1024],                       \
            2.f*Zin[basep + (size_t)(k*48 + 2*j + 1)*1024]);                  \
        xq[j] = __builtin_amdgcn_cvt_pkrtz(                                   \
            2.f*Zin[baseq + (size_t)(k*48 + 2*j)*1024],                       \
            2.f*Zin[baseq + (size_t)(k*48 + 2*j + 1)*1024]);                  \
    }                                                                         \
    xp[24] = __builtin_amdgcn_cvt_pkrtz(-1.f, -1.f);                          \
    xp[25] = xp[24]; xq[24] = xp[24]; xq[25] = xp[24];                        \
    const int sm = tid & 63, p8 = tid >> 6;                                   \
    unsigned w0, w1, w2, w3, w4, w5; unsigned short wc2;

#define SLOAD(m0) do {                                                        \
        const float* _p = Cb + (size_t)((m0) + sm)*384 + k*48 + p8*12;        \
        float4 va = *(const float4*)(_p);                                     \
        float4 vb = *(const float4*)(_p + 4);                                 \
        float4 vc = *(const float4*)(_p + 8);                                 \
        w0 = h2u(__builtin_amdgcn_cvt_pkrtz(va.x, va.y));                     \
        w1 = h2u(__builtin_amdgcn_cvt_pkrtz(va.z, va.w));                     \
        w2 = h2u(__builtin_amdgcn_cvt_pkrtz(vb.x, vb.y));                     \
        w3 = h2u(__builtin_amdgcn_cvt_pkrtz(vb.z, vb.w));                     \
        w4 = h2u(__builtin_amdgcn_cvt_pkrtz(vc.x, vc.y));                     \
        w5 = h2u(__builtin_amdgcn_cvt_pkrtz(vc.z, vc.w));                     \
        float c2 = va.x*va.x + va.y*va.y + va.z*va.z + va.w*va.w              \
                 + vb.x*vb.x + vb.y*vb.y + vb.z*vb.z + vb.w*vb.w              \
                 + vc.x*vc.x + vc.y*vc.y + vc.z*vc.z + vc.w*vc.w;             \
        wc2 = (unsigned short)(h2u(__builtin_amdgcn_cvt_pkrtz(c2, 0.f)) & 0xFFFF); \
    } while (0)

#define SWRITE(b) do {                                                        \
        *(uint2*)&cbuf[b][sm][p8*12    ] = make_uint2(w0, w1);                \
        *(uint2*)&cbuf[b][sm][p8*12 + 4] = make_uint2(w2, w3);                \
        *(uint2*)&cbuf[b][sm][p8*12 + 8] = make_uint2(w4, w5);                \
        cbuf[b][sm][48 + p8] = wc2;                                           \
    } while (0)

#define LOADCW(b, m)                                                          \
    unsigned cw[24]; uint2 c2w;                                               \
    {   uint4 q0 = *(const uint4*)&cbuf[b][m][0];                             \
        uint4 q1 = *(const uint4*)&cbuf[b][m][8];                             \
        uint4 q2 = *(const uint4*)&cbuf[b][m][16];                            \
        uint4 q3 = *(const uint4*)&cbuf[b][m][24];                            \
        uint4 q4 = *(const uint4*)&cbuf[b][m][32];                            \
        uint4 q5 = *(const uint4*)&cbuf[b][m][40];                            \
        cw[0]=q0.x;  cw[1]=q0.y;  cw[2]=q0.z;  cw[3]=q0.w;                    \
        cw[4]=q1.x;  cw[5]=q1.y;  cw[6]=q1.z;  cw[7]=q1.w;                    \
        cw[8]=q2.x;  cw[9]=q2.y;  cw[10]=q2.z; cw[11]=q2.w;                   \
        cw[12]=q3.x; cw[13]=q3.y; cw[14]=q3.z; cw[15]=q3.w;                   \
        cw[16]=q4.x; cw[17]=q4.y; cw[18]=q4.z; cw[19]=q4.w;                   \
        cw[20]=q5.x; cw[21]=q5.y; cw[22]=q5.z; cw[23]=q5.w;                   \
        c2w = *(const uint2*)&cbuf[b][m][48];                                 \
    }

// dots for BOTH rows, macro (no array-by-pointer: all indices compile-time)
#define DOT48(SP, SQ)                                                         \
    float SP, SQ;                                                             \
    {   float aP = 0.f, bP = 0.f, aQ = 0.f, bQ = 0.f;                         \
        _Pragma("unroll")                                                     \
        for (int j = 0; j < 24; j += 2) {                                     \
            aP = fdot2f(u2h(cw[j]),   xp[j],   aP);                           \
            bP = fdot2f(u2h(cw[j+1]), xp[j+1], bP);                           \
            aQ = fdot2f(u2h(cw[j]),   xq[j],   aQ);                           \
            bQ = fdot2f(u2h(cw[j+1]), xq[j+1], bQ);                           \
        }                                                                     \
        aP = fdot2f(u2h(c2w.x), xp[24], aP);                                  \
        bP = fdot2f(u2h(c2w.y), xp[25], bP);                                  \
        aQ = fdot2f(u2h(c2w.x), xq[24], aQ);                                  \
        bQ = fdot2f(u2h(c2w.y), xq[25], bQ);                                  \
        SP = aP + bP; SQ = aQ + bQ; }

// =========================== kernel 1: stats ===========================
__global__ __launch_bounds__(256, 4)
void pq_stats(const float* __restrict__ Zin, const float* __restrict__ Cb,
              float2* __restrict__ Ws)
{
    __shared__ __align__(16) unsigned short cbuf[2][64][56];
    PQ_PROLOG

    float Zp = 0.f, Tp = 0.f, Zq = 0.f, Tq = 0.f;
    SLOAD(0); SWRITE(0);
    __syncthreads();
    int buf = 0;
#pragma unroll 1
    for (int t = 0; t < 32; ++t) {
        if (t < 31) SLOAD((t + 1)*64);
#pragma unroll
        for (int mb = 0; mb < 8; ++mb) {
            const int m = mb*8 + cs;
            LOADCW(buf, m);
            DOT48(sp, sq);
            float e1 = __expf(sp), e2 = __expf(sq);
            Zp += e1; Tp = fmaf(e1, sp, Tp);
            Zq += e2; Tq = fmaf(e2, sq, Tq);
        }
        if (t < 31) SWRITE(buf ^ 1);
        __syncthreads();
        buf ^= 1;
    }
    // reduce over the 8 code-classes (lane bits 3..5)
#pragma unroll
    for (int off = 8; off < 64; off <<= 1) {
        Zp += __shfl_xor(Zp, off); Tp += __shfl_xor(Tp, off);
        Zq += __shfl_xor(Zq, off); Tq += __shfl_xor(Tq, off);
    }
    if (cs == 0) {
        float i1 = 1.f/Zp, i2 = 1.f/Zq;
        Ws[(k << 13) + pairIdx] = make_float2(i1, Tp*i1 - __logf(Zp));
        Ws[(k << 13) + nq]      = make_float2(i2, Tq*i2 - __logf(Zq));
    }
}

// =========================== kernel 2: output ===========================
__global__ __launch_bounds__(256, 3)
void pq_out(const float* __restrict__ Zin, const float* __restrict__ Cb,
            const float2* __restrict__ Ws, float* __restrict__ Out)
{
    __shared__ __align__(16) unsigned short cbuf[2][64][56];
    __shared__ float jred[4];
    PQ_PROLOG

    const float2 wp = Ws[(k << 13) + pairIdx];
    const float2 wq = Ws[(k << 13) + nq];
    const float izp = wp.x, izq = wq.x;

    f16x2 Op[24], Oq[24];
#pragma unroll
    for (int j = 0; j < 24; ++j) { Op[j] = u2h(0u); Oq[j] = u2h(0u); }
    float cross = 0.f;

    SLOAD(0); SWRITE(0);
    __syncthreads();
    int buf = 0;
#pragma unroll 1
    for (int t = 0; t < 32; ++t) {
        if (t < 31) SLOAD((t + 1)*64);
#pragma unroll
        for (int mb = 0; mb < 8; ++mb) {
            const int m = mb*8 + cs;
            LOADCW(buf, m);
            DOT48(sp, sq);
            float e1 = __expf(sp), e2 = __expf(sq);
            float ssum = fmaf(e1, izp, e2*izq);           // p + q
            cross = fmaf(ssum, __logf(fmaf(0.5f, ssum, 1e-12f)), cross);
            f16x2 ep = __builtin_amdgcn_cvt_pkrtz(e1, e1);
            f16x2 eq = __builtin_amdgcn_cvt_pkrtz(e2, e2);
#pragma unroll
            for (int j = 0; j < 24; ++j) {                // v_pk_fma_f16
                Op[j] = u2h(cw[j])*ep + Op[j];
                Oq[j] = u2h(cw[j])*eq + Oq[j];
            }
        }
        if (t < 31) SWRITE(buf ^ 1);
        __syncthreads();
        buf ^= 1;
    }

    // ---- JSD: cross covers this lane's m-class only; ent once per pair ----
    float jloc = ((cs == 0) ? (wp.y + wq.y) : 0.f) - cross;
#pragma unroll
    for (int off = 1; off < 64; off <<= 1) jloc += __shfl_xor(jloc, off);
    if (lane == 0) jred[wv] = jloc;
    __syncthreads();
    if (tid == 0)
        atomicAdd(Out + JSD_IDX,
                  (jred[0] + jred[1] + jred[2] + jred[3]) * (0.5f / 32768.f));

    // ---- reduce O over code-classes (packed f16 adds, static indices) ----
#pragma unroll
    for (int off = 8; off < 64; off <<= 1)
#pragma unroll
        for (int j = 0; j < 24; ++j) {
            Op[j] = Op[j] + u2h(__shfl_xor(h2u(Op[j]), off));
            Oq[j] = Oq[j] + u2h(__shfl_xor(h2u(Oq[j]), off));
        }

    // ---- store: lane cs stores dims [cs*6, cs*6+6), STATIC indices ----
#define STORE3(J0) {                                                          \
        _Pragma("unroll")                                                     \
        for (int r = 0; r < 3; ++r) {                                         \
            f16x2 vp = Op[(J0) + r], vq = Oq[(J0) + r];                       \
            const int ch = k*48 + 2*((J0) + r);                               \
            Out[basep + (size_t)(ch    )*1024] = (float)vp.x * izp;           \
            Out[basep + (size_t)(ch + 1)*1024] = (float)vp.y * izp;           \
            Out[baseq + (size_t)(ch    )*1024] = (float)vq.x * izq;           \
            Out[baseq + (size_t)(ch + 1)*1024] = (float)vq.y * izq;           \
        } }
    if      (cs == 0) STORE3(0)
    else if (cs == 1) STORE3(3)
    else if (cs == 2) STORE3(6)
    else if (cs == 3) STORE3(9)
    else if (cs == 4) STORE3(12)
    else if (cs == 5) STORE3(15)
    else if (cs == 6) STORE3(18)
    else              STORE3(21)
}

extern "C" void kernel_launch(void* const* d_in, const int* in_sizes, int n_in,
                              void* d_out, int out_size, void* d_ws, size_t ws_size,
                              hipStream_t stream)
{
    const float* z = (const float*)d_in[0];
    const float* C = (const float*)d_in[1];
    float* out = (float*)d_out;
    float2* ws = (float2*)d_ws;   // 8 k * 8192 rows * (1/Z, ent) = 512 KB

    hipMemsetAsync(out + JSD_IDX, 0, sizeof(float), stream);

    pq_stats<<<dim3(1024), dim3(256), 0, stream>>>(z, C, ws);
    pq_out  <<<dim3(1024), dim3(256), 0, stream>>>(z, C, ws, out);
}

// Round 13
// 195.172 us; speedup vs baseline: 26.9872x; 26.9872x over previous
//
#include <hip/hip_runtime.h>

// Soft product quantizer — MFMA via BUILTINS + probe-calibrated layout.
// z:(8,384,32,32) f32, C:(2048,384) f32. 4096 pairs (n,n+4096) x K=8, d=48, M=2048.
// s = 2<x,c> - |c|^2 (x^2 cancels; |s| small -> no max-subtract).
// Probe MFMAs label every D-slot: mS[j] = A-row label, rS[j] = B-col label
// (exact integers; valid under ANY bijective fragment layout because the real
// GEMMs use the same A/B addressing). Pass1: S -> Z,T via LDS atomics keyed
// rS. Pass2: S again -> P scattered to plds[xrow][code] at measured coords ->
// O = P*C with the same mfma recipe -> store at (mS, dt*16+rS). JSD identity:
// jsd = [sum ent - sum (p+q)log((p+q)/2+eps)] * 0.5/32768.

typedef __attribute__((ext_vector_type(8))) short short8;
typedef __attribute__((ext_vector_type(4))) float f32x4;

#define Z_BCH   (384*1024)
#define JSD_IDX 3145728

__device__ __forceinline__ f32x4 mfma32(short8 a, short8 b, f32x4 c) {
    return __builtin_amdgcn_mfma_f32_16x16x32_bf16(a, b, c, 0, 0, 0);
}
__device__ __forceinline__ unsigned short f2bf(float x) {
    unsigned u = __float_as_uint(x);
    u += 0x7FFF + ((u >> 16) & 1);          // RNE
    return (unsigned short)(u >> 16);
}
__device__ __forceinline__ unsigned pk2bf(float a, float b) {
    return (unsigned)f2bf(a) | ((unsigned)f2bf(b) << 16);
}
__device__ __forceinline__ float bf2f(unsigned short h) {
    return __uint_as_float(((unsigned)h) << 16);
}

// LDS (bytes):
//  cs  [64][72] u16 @0      (9216)  codes: d0..47, 48/49=-c2/2 hi/lo, 50..63=0
//  ct  [48][72] u16 @9216   (6912)  C^T [d][m]
//  plds per-wave [32][72] u16 @16128+wv*4608 (18432)  P rows: 16 p + 16 q
//  xs  [128][72] u16 @0     (18432) prologue overlay only
//  @34560 ztP[64] ttP ztQ ttQ (1024) | @35584 ipzP ipzQ (512)
//  @36096 entP entQ (512) | @36608 misc[4] -> 36624 total
__global__ __launch_bounds__(256)
void pq_mfb(const float* __restrict__ Zin, const float* __restrict__ Cb,
            float* __restrict__ Out)
{
    __shared__ __align__(16) unsigned char smem[36640];
    unsigned short* cs = (unsigned short*)smem;
    unsigned short* ct = (unsigned short*)(smem + 9216);
    unsigned short* xs = (unsigned short*)smem;
    float* ztP  = (float*)(smem + 34560);
    float* ttP  = (float*)(smem + 34816);
    float* ztQ  = (float*)(smem + 35072);
    float* ttQ  = (float*)(smem + 35328);
    float* ipzP = (float*)(smem + 35584);
    float* ipzQ = (float*)(smem + 35840);
    float* entP = (float*)(smem + 36096);
    float* entQ = (float*)(smem + 36352);
    float* misc = (float*)(smem + 36608);

    const int tid  = threadIdx.x;
    const int lane = tid & 63;
    const int wv   = tid >> 6;
    const int lr   = lane & 15;
    const int lg   = lane >> 4;
    const int pg   = blockIdx.x & 63;   // 64 pair-groups (64 pairs each)
    const int k    = blockIdx.x >> 6;   // subspace

    unsigned short* plds = (unsigned short*)(smem + 16128 + wv*4608);

    // ---------- layout probes (builtin MFMA, register-only, exact) ----------
    short8 av, on;
#pragma unroll
    for (int i = 0; i < 8; ++i) { av[i] = (short)f2bf((float)lr); on[i] = (short)0x3F80; }
    f32x4 zf4 = {0.f,0.f,0.f,0.f};
    f32x4 dm = mfma32(av, on, zf4);     // slot j -> 32 * (A-row label)
    f32x4 dr = mfma32(on, av, zf4);     // slot j -> 32 * (B-col label)
    int mS[4], rS[4];
#pragma unroll
    for (int j = 0; j < 4; ++j) {
        mS[j] = ((int)(dm[j]*0.03125f + 0.5f)) & 15;
        rS[j] = ((int)(dr[j]*0.03125f + 0.5f)) & 15;
    }

    // ---------- prologue: zero stats + xs; x -> xs -> register B-frags ----------
    if (tid < 256) ((float*)(smem + 34560))[tid] = 0.f;    // ztP..ttQ
    for (int i = tid; i < 4608; i += 256) ((unsigned*)smem)[i] = 0u;
    __syncthreads();
    for (int i = tid; i < 6144; i += 256) {                // 128 rows x 48 dims
        int row = i & 127, d = i >> 7;
        int n = pg*64 + (row & 63) + ((row & 64) ? 4096 : 0);
        xs[row*72 + d] = f2bf(Zin[(size_t)(n >> 10)*Z_BCH + (k*48 + d)*1024 + (n & 1023)]);
    }
    if (tid < 128) { xs[tid*72 + 48] = 0x3F80; xs[tid*72 + 49] = 0x3F80; }
    __syncthreads();
    short8 xf[2][2];   // [p/q][k-half]; wave rows: p = wv*16+lr, q = +64
#pragma unroll
    for (int kh = 0; kh < 2; ++kh) {
        xf[0][kh] = *(const short8*)(xs + (wv*16 + lr)*72 + kh*32 + lg*8);
        xf[1][kh] = *(const short8*)(xs + (64 + wv*16 + lr)*72 + kh*32 + lg*8);
    }
    __syncthreads();   // xs region reusable (cs/ct/plds overlay)

    const int sm = tid & 63, p8 = tid >> 6;
    auto stage = [&](int m0, bool doCT) {
        const float4* crow = (const float4*)(Cb + (size_t)(m0 + sm)*384 + k*48);
        float4 va = crow[p8*3+0], vb = crow[p8*3+1], vc = crow[p8*3+2];
        unsigned u0 = pk2bf(va.x, va.y), u1 = pk2bf(va.z, va.w);
        unsigned u2 = pk2bf(vb.x, vb.y), u3 = pk2bf(vb.z, vb.w);
        unsigned u4 = pk2bf(vc.x, vc.y), u5 = pk2bf(vc.z, vc.w);
        const int d0 = p8*12;
        *(uint2*)(cs + sm*72 + d0 + 0) = make_uint2(u0, u1);
        *(uint2*)(cs + sm*72 + d0 + 4) = make_uint2(u2, u3);
        *(uint2*)(cs + sm*72 + d0 + 8) = make_uint2(u4, u5);
        if (doCT) {
            ct[(d0+ 0)*72 + sm] = (unsigned short)u0;
            ct[(d0+ 1)*72 + sm] = (unsigned short)(u0 >> 16);
            ct[(d0+ 2)*72 + sm] = (unsigned short)u1;
            ct[(d0+ 3)*72 + sm] = (unsigned short)(u1 >> 16);
            ct[(d0+ 4)*72 + sm] = (unsigned short)u2;
            ct[(d0+ 5)*72 + sm] = (unsigned short)(u2 >> 16);
            ct[(d0+ 6)*72 + sm] = (unsigned short)u3;
            ct[(d0+ 7)*72 + sm] = (unsigned short)(u3 >> 16);
            ct[(d0+ 8)*72 + sm] = (unsigned short)u4;
            ct[(d0+ 9)*72 + sm] = (unsigned short)(u4 >> 16);
            ct[(d0+10)*72 + sm] = (unsigned short)u5;
            ct[(d0+11)*72 + sm] = (unsigned short)(u5 >> 16);
        }
        if (tid < 64) {   // c2 (L1-hot re-read); pads into cols 48..63
            const float4* cr2 = (const float4*)(Cb + (size_t)(m0 + tid)*384 + k*48);
            float c2 = 0.f;
#pragma unroll
            for (int i = 0; i < 12; ++i) {
                float4 v = cr2[i];
                c2 += v.x*v.x + v.y*v.y + v.z*v.z + v.w*v.w;
            }
            float mh = -0.5f*c2;
            unsigned short hi = f2bf(mh);
            unsigned short lo = f2bf(mh - bf2f(hi));
            *(uint2*)(cs + tid*72 + 48) = make_uint2((unsigned)hi | ((unsigned)lo << 16), 0u);
            *(uint2*)(cs + tid*72 + 52) = make_uint2(0u, 0u);
            *(uint2*)(cs + tid*72 + 56) = make_uint2(0u, 0u);
            *(uint2*)(cs + tid*72 + 60) = make_uint2(0u, 0u);
        }
    };

    // ---------------- pass 1: softmax stats (per-slot, attribution-free) ----------------
    float zp[4] = {0,0,0,0}, tp[4] = {0,0,0,0}, zq[4] = {0,0,0,0}, tq[4] = {0,0,0,0};
#pragma unroll 1
    for (int t = 0; t < 32; ++t) {
        stage(t*64, false);
        __syncthreads();
#pragma unroll
        for (int mt = 0; mt < 4; ++mt) {
            short8 a0 = *(const short8*)(cs + (mt*16 + lr)*72 + lg*8);
            short8 a1 = *(const short8*)(cs + (mt*16 + lr)*72 + 32 + lg*8);
            f32x4 accP = {0.f,0.f,0.f,0.f}, accQ = {0.f,0.f,0.f,0.f};
            accP = mfma32(a0, xf[0][0], accP);
            accP = mfma32(a1, xf[0][1], accP);
            accQ = mfma32(a0, xf[1][0], accQ);
            accQ = mfma32(a1, xf[1][1], accQ);
#pragma unroll
            for (int j = 0; j < 4; ++j) {
                float sp = 2.f*accP[j], sq = 2.f*accQ[j];
                float e1 = __expf(sp), e2 = __expf(sq);
                zp[j] += e1; tp[j] = fmaf(e1, sp, tp[j]);
                zq[j] += e2; tq[j] = fmaf(e2, sq, tq[j]);
            }
        }
        __syncthreads();
    }
    // per-row totals via LDS atomics keyed by measured rS
#pragma unroll
    for (int j = 0; j < 4; ++j) {
        int r = wv*16 + rS[j];
        atomicAdd(ztP + r, zp[j]); atomicAdd(ttP + r, tp[j]);
        atomicAdd(ztQ + r, zq[j]); atomicAdd(ttQ + r, tq[j]);
    }
    __syncthreads();
    if (tid < 64) {
        float z1 = ztP[tid], t1 = ttP[tid];
        float z2 = ztQ[tid], t2 = ttQ[tid];
        float i1 = 1.f/z1, i2 = 1.f/z2;
        ipzP[tid] = i1; entP[tid] = t1*i1 - __logf(z1);
        ipzQ[tid] = i2; entQ[tid] = t2*i2 - __logf(z2);
    }
    __syncthreads();
    float izp_s[4], izq_s[4];
#pragma unroll
    for (int j = 0; j < 4; ++j) {
        izp_s[j] = ipzP[wv*16 + rS[j]];
        izq_s[j] = ipzQ[wv*16 + rS[j]];
    }

    // ---------------- pass 2: recompute S, P -> plds (measured coords), O-MFMA ----------------
    f32x4 Op[3], Oq[3];
#pragma unroll
    for (int dt = 0; dt < 3; ++dt) { Op[dt] = (f32x4){0.f,0.f,0.f,0.f}; Oq[dt] = (f32x4){0.f,0.f,0.f,0.f}; }
    float cross = 0.f;

#pragma unroll 1
    for (int t = 0; t < 32; ++t) {
        stage(t*64, true);
        __syncthreads();
#pragma unroll
        for (int mt = 0; mt < 4; ++mt) {
            short8 a0 = *(const short8*)(cs + (mt*16 + lr)*72 + lg*8);
            short8 a1 = *(const short8*)(cs + (mt*16 + lr)*72 + 32 + lg*8);
            f32x4 accP = {0.f,0.f,0.f,0.f}, accQ = {0.f,0.f,0.f,0.f};
            accP = mfma32(a0, xf[0][0], accP);
            accP = mfma32(a1, xf[0][1], accP);
            accQ = mfma32(a0, xf[1][0], accQ);
            accQ = mfma32(a1, xf[1][1], accQ);
#pragma unroll
            for (int j = 0; j < 4; ++j) {
                float e1 = __expf(2.f*accP[j]);
                float e2 = __expf(2.f*accQ[j]);
                float p = e1*izp_s[j], q = e2*izq_s[j];
                float ss = p + q;
                cross = fmaf(ss, __logf(fmaf(0.5f, ss, 1e-12f)), cross);
                plds[rS[j]*72        + mt*16 + mS[j]] = f2bf(e1);
                plds[(16 + rS[j])*72 + mt*16 + mS[j]] = f2bf(e2);
            }
        }
        // O = P*C with the SAME mfma recipe (only the probe-measured claim used)
#pragma unroll
        for (int kh = 0; kh < 2; ++kh) {
            short8 pA = *(const short8*)(plds + lr*72        + kh*32 + lg*8);
            short8 qA = *(const short8*)(plds + (16 + lr)*72 + kh*32 + lg*8);
#pragma unroll
            for (int dt = 0; dt < 3; ++dt) {
                short8 cB = *(const short8*)(ct + (dt*16 + lr)*72 + kh*32 + lg*8);
                Op[dt] = mfma32(pA, cB, Op[dt]);
                Oq[dt] = mfma32(qA, cB, Oq[dt]);
            }
        }
        __syncthreads();
    }

    // ---------------- JSD ----------------
#pragma unroll
    for (int off = 1; off < 64; off <<= 1) cross += __shfl_xor(cross, off);
    if (lane == 0) misc[wv] = cross;
    __syncthreads();
    if (tid == 0) {
        float es = 0.f;
        for (int r = 0; r < 64; ++r) es += entP[r] + entQ[r];
        float cr = misc[0] + misc[1] + misc[2] + misc[3];
        atomicAdd(Out + JSD_IDX, (es - cr) * (0.5f/32768.f));
    }

    // ---------------- store O at measured coordinates ----------------
#pragma unroll
    for (int dt = 0; dt < 3; ++dt)
#pragma unroll
        for (int j = 0; j < 4; ++j) {
            int xr = mS[j];                       // xrow label (A side of O-GEMM)
            int np = pg*64 + wv*16 + xr;
            int nq = np + 4096;
            int ch = k*48 + dt*16 + rS[j];        // d label (B side)
            float vP = Op[dt][j] * ipzP[wv*16 + xr];
            float vQ = Oq[dt][j] * ipzQ[wv*16 + xr];
            Out[(size_t)(np >> 10)*Z_BCH + (size_t)ch*1024 + (np & 1023)] = vP;
            Out[(size_t)(nq >> 10)*Z_BCH + (size_t)ch*1024 + (nq & 1023)] = vQ;
        }
}

extern "C" void kernel_launch(void* const* d_in, const int* in_sizes, int n_in,
                              void* d_out, int out_size, void* d_ws, size_t ws_size,
                              hipStream_t stream)
{
    const float* z = (const float*)d_in[0];
    const float* C = (const float*)d_in[1];
    float* out = (float*)d_out;

    hipMemsetAsync(out + JSD_IDX, 0, sizeof(float), stream);

    // 64 pair-groups (64 pairs each) x 8 subspaces
    pq_mfb<<<dim3(512), dim3(256), 0, stream>>>(z, C, out);
}